// Round 7
// baseline (1072.115 us; speedup 1.0000x reference)
//
#include <hip/hip_runtime.h>

// SNN layer, round 14: int8 Ozaki GEMM — A direct-to-register, B-only LDS.
//
//  Evidence r9-r13: util pinned 40-47% across 4 schedules; r13 at 16 waves/CU
//  STILL 47%. Binder isolated: LDS bank BW. Per CU-round (r13): frag reads
//  (2x amp: wave pairs share frags) + DMA writes = 240KB ~ 2820cy at 85B/cy
//  > 2194cy matrix work. Bytes/MFMA (682B) caps util ~47% regardless of
//  schedule.
//
//  Fix: xp planes ARE the per-lane fragment image -> read A frags straight
//  from global (L2/L3-hot, 16x o-tile reuse) to registers; A never touches
//  LDS. B (256x reuse) stays DMA-staged, TRIPLE-buffered (30KB):
//   - iter kb: issue [5x A(kb+1)->regs, 3x B(kb+1)->slot (kb+1)%3] (8 loads,
//     uniform), vmcnt(8) (counted, waits batch kb only), barrier, compute.
//   - 3-slot proof: X issues DMA(kb+1)->slot s=(kb+1)%3 after crossing
//     barrier(kb-1); laggards are >= iter kb-1 reading slot (kb-1)%3 != s;
//     s's tenant B(kb-2) was read in compute(kb-2), which precedes every
//     wave's arrival at barrier(kb-1). No overlap.
//   - compute: rolling B frags (ds_read B(j+1) under MFMA group j) -> only
//     head read stalls (~150cy). LDS/round 90KB (1060cy) < matrix 1645cy.
//  Regs: acc 80 + A even/odd 40 + B 8 + misc ~150 -> bounds(256,3).
//
//  Numerics unchanged (absmax 0.0 proven, 15 pairs c<=4). Prepasses + scan
//  unchanged; xp/wp layouts identical to r13.
//
//  ws: vstate 256KB | SB 8KB | wp 5.2MB | SA | xp (tiled) | cur (tca=512: 219MB)

#define NB 32
#define NI 1024
#define NO 1024
#define NT 1000
#define NS 5          // slices per operand (7 bits each, base 128)
#define BT 64         // t rows per block tile
#define BO 64         // o cols per block tile
#define KI 32         // k per pipeline stage
#define NKB (NI/KI)   // 32 k-blocks
#define TILEB (NS*2*64*16)   // 10240 B per (kb, matrix): [s][kc][row][16]

typedef int i32x4  __attribute__((ext_vector_type(4)));
typedef int i32x16 __attribute__((ext_vector_type(16)));

typedef const __attribute__((address_space(1))) void GVOID;
typedef __attribute__((address_space(3))) void LVOID;
#define GLDS16(g, l) __builtin_amdgcn_global_load_lds((GVOID*)(g), (LVOID*)(l), 16, 0, 0)

// ---- per-o column scale of w: SB = 2^(e+1) > colmax, plus 1/SB ----
__global__ void snn_wscale(const float* __restrict__ w, float* __restrict__ sb)
{
    __shared__ float red[4][64];
    const int tid = threadIdx.x;
    const int ol = tid & 63, iq = tid >> 6;
    const int o = blockIdx.x * 64 + ol;
    float m = 0.f;
    for (int i = iq; i < NI; i += 4) m = fmaxf(m, fabsf(w[(size_t)i * NO + o]));
    red[iq][ol] = m;
    __syncthreads();
    if (iq == 0) {
        m = fmaxf(fmaxf(red[0][ol], red[1][ol]), fmaxf(red[2][ol], red[3][ol]));
        const int e = (__float_as_uint(m) >> 23) & 255;
        float S = 0.f, Si = 0.f;
        if (e) {
            S  = __uint_as_float((unsigned)(e + 1) << 23);
            Si = __uint_as_float((unsigned)(253 - e) << 23);
        }
        sb[o] = S;
        sb[NO + o] = Si;
    }
}

// ---- slice w into tiled planes wp[otile][kb][s][kc][o][16] (5 slices) ----
__global__ void snn_wslice(const float* __restrict__ w, const float* __restrict__ sb,
                           signed char* __restrict__ wp)
{
    __shared__ int sldw[NS][64][16];   // XOR-swizzled dword cols
    const int tid = threadIdx.x;
    const int ol = tid & 63, iq = tid >> 6;
    const int o0 = blockIdx.x * 64, ic = blockIdx.y * 64;
    const float inv = sb[NO + o0 + ol];
#pragma unroll
    for (int q4 = 0; q4 < 16; q4 += 4) {
        int pk[NS] = {0, 0, 0, 0, 0};
#pragma unroll
        for (int j = 0; j < 4; ++j) {
            const int i = ic + iq * 16 + q4 + j;
            float wv = w[(size_t)i * NO + o0 + ol] * inv;   // exact (pow2 scale)
#pragma unroll
            for (int s = 0; s < NS; ++s) {
                const float f = wv * 128.f;     // exact, |f|<128
                const int a = (int)f;           // trunc in [-127,127]
                wv = f - (float)a;              // exact remainder
                pk[s] |= (a & 255) << (8 * j);
            }
        }
        const int cdw = (iq * 16 + q4) >> 2;
#pragma unroll
        for (int s = 0; s < NS; ++s) sldw[s][ol][cdw ^ (ol & 15)] = pk[s];
    }
    __syncthreads();
    // 5120 dwords out: [kbi(2)][s(5)][kc(2)][row(64)][d4(4)], contiguous per kbi
    signed char* tb = wp + (size_t)blockIdx.x * (NKB * TILEB) + (size_t)(ic >> 5) * TILEB;
#pragma unroll
    for (int p = 0; p < 20; ++p) {
        const int idx = p * 256 + tid;
        const int kbi = idx >= 2560;
        const int ld  = idx - (kbi ? 2560 : 0);
        const int s  = ld >> 9;
        const int kc = (ld >> 8) & 1;
        const int r  = (ld >> 2) & 63;
        const int d4 = ld & 3;
        *(int*)&tb[(size_t)kbi * TILEB + (size_t)ld * 4] =
            sldw[s][r][(kbi * 8 + kc * 4 + d4) ^ (r & 15)];
    }
}

// ---- per-(b,t) scale SA = 2^(e+1) > rowmax ----
__global__ void snn_xscale(const float* __restrict__ x, float* __restrict__ sa,
                           int t0, int tca)
{
    __shared__ float red[4][64];
    const int tid = threadIdx.x;
    const int tl = tid & 63, iq = tid >> 6;
    const int b = blockIdx.y;
    const int tt = blockIdx.x * 64;
    const int tg = t0 + tt + tl;
    const float* xb = x + (size_t)b * NI * NT;
    float m = 0.f;
    if (tg < NT)
        for (int i = iq; i < NI; i += 4) m = fmaxf(m, fabsf(xb[(size_t)i * NT + tg]));
    red[iq][tl] = m;
    __syncthreads();
    if (iq == 0) {
        m = fmaxf(fmaxf(red[0][tl], red[1][tl]), fmaxf(red[2][tl], red[3][tl]));
        const int e = (__float_as_uint(m) >> 23) & 255;
        sa[(size_t)b * tca + tt + tl] = e ? __uint_as_float((unsigned)(e + 1) << 23) : 0.f;
    }
}

// ---- slice x into tiled planes xp[b][tile][kb][s][kc][t][16] (5 slices) ----
__global__ void snn_xslice(const float* __restrict__ x, const float* __restrict__ sa,
                           signed char* __restrict__ xp, int t0, int tca, int ntiles)
{
    __shared__ int sldw[NS][64][16];
    const int tid = threadIdx.x;
    const int tl = tid & 63, iq = tid >> 6;
    const int b = blockIdx.y;
    const int tile = blockIdx.x;
    const int tg = t0 + tile * 64 + tl;
    const bool valid = (tg < NT);
    const float* xb = x + (size_t)b * NI * NT;
    const float S = sa[(size_t)b * tca + tile * 64 + tl];
    const float inv = (S > 0.f)
        ? __uint_as_float((254u - (__float_as_uint(S) >> 23)) << 23) : 0.f;  // exact 1/S
    signed char* tb = xp + (size_t)(b * ntiles + tile) * (NKB * TILEB);

    for (int c4 = 0; c4 < 4; ++c4) {
        const int ic = blockIdx.z * 256 + c4 * 64;
#pragma unroll
        for (int q4 = 0; q4 < 16; q4 += 4) {
            int pk[NS] = {0, 0, 0, 0, 0};
#pragma unroll
            for (int j = 0; j < 4; ++j) {
                const int i = ic + iq * 16 + q4 + j;
                float wv = valid ? xb[(size_t)i * NT + tg] * inv : 0.f;
#pragma unroll
                for (int s = 0; s < NS; ++s) {
                    const float f = wv * 128.f;
                    const int a = (int)f;
                    wv = f - (float)a;
                    pk[s] |= (a & 255) << (8 * j);
                }
            }
            const int cdw = (iq * 16 + q4) >> 2;
#pragma unroll
            for (int s = 0; s < NS; ++s) sldw[s][tl][cdw ^ (tl & 15)] = pk[s];
        }
        __syncthreads();
        signed char* kbb = tb + (size_t)(ic >> 5) * TILEB;
#pragma unroll
        for (int p = 0; p < 20; ++p) {
            const int idx = p * 256 + tid;
            const int kbi = idx >= 2560;
            const int ld  = idx - (kbi ? 2560 : 0);
            const int s  = ld >> 9;
            const int kc = (ld >> 8) & 1;
            const int r  = (ld >> 2) & 63;
            const int d4 = ld & 3;
            *(int*)&kbb[(size_t)kbi * TILEB + (size_t)ld * 4] =
                sldw[s][r][(kbi * 8 + kc * 4 + d4) ^ (r & 15)];
        }
        __syncthreads();
    }
}

// ---- int8 MFMA GEMM: 64x64 block, 4 waves of 32x32 ----
// A frags: global->reg (even/odd sets, 1-iter prefetch). B: 3-slot LDS DMA.
// Per iter: issue 8 loads, vmcnt(8), 1 barrier, rolling-B-frag MFMA compute.
__global__ __launch_bounds__(256, 3)
void snn_gemm_i8(const signed char* __restrict__ xp, const signed char* __restrict__ wp,
                 const float* __restrict__ sa, const float* __restrict__ sb,
                 double* __restrict__ cur, int t0, int tca, int ntiles)
{
    __shared__ signed char Bs[3][TILEB];   // 30 KB, B only

    const int tid  = threadIdx.x;
    const int lane = tid & 63;
    const int wave = tid >> 6;
    const int wm = (wave >> 1) * 32;
    const int wn = (wave & 1) * 32;
    const int l31 = lane & 31;
    const int hi  = lane >> 5;

    // bijective XCD-aware remap (m204); nwg = 512*ntiles, always % 8 == 0
    int lid = blockIdx.x + (int)gridDim.x * (blockIdx.y + (int)gridDim.y * blockIdx.z);
    {
        const int nwg = (int)(gridDim.x * gridDim.y * gridDim.z);
        const int q = nwg >> 3, r = nwg & 7;
        const int xcd = lid & 7, off = lid >> 3;
        lid = (xcd < r ? xcd * (q + 1) : r * (q + 1) + (xcd - r) * q) + off;
    }
    const int ox  = lid & 15;          // o-tile (gridDim.x == 16)
    const int rst = lid >> 4;
    const int ty  = rst % ntiles;      // t-tile
    const int b   = rst / ntiles;      // batch

    const int o0 = ox * BO;
    const int bt = ty * BT;

    i32x16 acc[NS];
#pragma unroll
    for (int c = 0; c < NS; ++c) acc[c] = (i32x16)0;

    // A: per-lane fragment address in the pre-tiled global image
    const signed char* Ag = xp + (size_t)(b * ntiles + ty) * (NKB * TILEB)
                               + hi * 1024 + (wm + l31) * 16;   // + kb*TILEB + s*2048
    // B: per-lane DMA source; LDS frag base
    const signed char* Bg = wp + (size_t)ox * (NKB * TILEB) + lane * 16;
    const int bbase = hi * 1024 + (wn + l31) * 16;              // + s*2048 in slot

    // issue batch for k-block 'src': 5 A-frag loads -> aset, 3 B DMA -> slot.
    // chunks (3*wave+u)%10: waves 0-3 cover 0..9; wave3 re-DMAs 0,1 (benign,
    // identical bytes). Uniform 8 vmcnt events per wave per batch.
#define ISSUE(src, aset, slot) do {                                            \
    const signed char* As_ = Ag + (size_t)(src) * TILEB;                       \
    _Pragma("unroll")                                                          \
    for (int s = 0; s < NS; ++s)                                               \
        aset[s] = *(const i32x4*)(As_ + s * 2048);                             \
    const signed char* Bsrc_ = Bg + (size_t)(src) * TILEB;                     \
    _Pragma("unroll")                                                          \
    for (int u = 0; u < 3; ++u) {                                              \
        int ck = 3 * wave + u; if (ck >= 10) ck -= 10;                         \
        GLDS16(Bsrc_ + ck * 1024, &Bs[slot][0] + ck * 1024);                   \
    } } while (0)

    // compute k-block from A regs + B slot: rolling B frags under MFMA groups.
    // pair (i,j): class c=i+j<=4 -> acc[c]; group j's 5-j MFMAs cover read j+1.
#define COMPUTE(aset, slot) do {                                               \
    const signed char* Bb_ = &Bs[slot][0];                                     \
    i32x4 bcur = *(const i32x4*)&Bb_[bbase];                                   \
    _Pragma("unroll")                                                          \
    for (int j = 0; j < NS; ++j) {                                             \
        i32x4 bnext = bcur;                                                    \
        if (j + 1 < NS) bnext = *(const i32x4*)&Bb_[bbase + (j + 1) * 2048];   \
        __builtin_amdgcn_s_setprio(1);                                         \
        _Pragma("unroll")                                                      \
        for (int i = 0; i + j < NS; ++i)                                       \
            acc[i + j] = __builtin_amdgcn_mfma_i32_32x32x32_i8(                \
                aset[i], bcur, acc[i + j], 0, 0, 0);                           \
        __builtin_amdgcn_s_setprio(0);                                         \
        bcur = bnext;                                                          \
    } } while (0)

    i32x4 aE[NS], aO[NS];

    // prologue: batch(0) -> aE, slot 0
    ISSUE(0, aE, 0);
    __builtin_amdgcn_sched_barrier(0);

    int sl_w = 1;   // slot for next issued B
    int sl_r = 0;   // slot read this iter
    for (int kb = 0; kb < NKB; kb += 2) {
        // even iter kb: compute aE, issue batch(kb+1) -> aO
        ISSUE(kb + 1, aO, sl_w);               // kb<=30 -> kb+1<=31 always valid
        sl_w = (sl_w == 2) ? 0 : sl_w + 1;
        __builtin_amdgcn_sched_barrier(0);
        asm volatile("s_waitcnt vmcnt(8)" ::: "memory");   // batch(kb) landed
        __builtin_amdgcn_s_barrier();
        COMPUTE(aE, sl_r);
        sl_r = (sl_r == 2) ? 0 : sl_r + 1;

        // odd iter kb+1: compute aO, issue batch(kb+2) -> aE
        if (kb + 2 < NKB) {
            ISSUE(kb + 2, aE, sl_w);
            sl_w = (sl_w == 2) ? 0 : sl_w + 1;
            __builtin_amdgcn_sched_barrier(0);
            asm volatile("s_waitcnt vmcnt(8)" ::: "memory");
        } else {
            asm volatile("s_waitcnt vmcnt(0)" ::: "memory");   // final drain
        }
        __builtin_amdgcn_s_barrier();
        COMPUTE(aO, sl_r);
        sl_r = (sl_r == 2) ? 0 : sl_r + 1;
    }
#undef ISSUE
#undef COMPUTE

    // Probe D reg->row mapping (epilogue). A=I(32x32), B[k][n]=k => D[m][n]=m.
    int prow[16];
    {
        i32x4 pa, pb;
#pragma unroll
        for (int q = 0; q < 4; ++q) {
            int va = 0, vb = 0;
#pragma unroll
            for (int jj = 0; jj < 4; ++jj) {
                const int k = 16 * hi + q * 4 + jj;
                if (l31 == k) va |= 1 << (8 * jj);
                vb |= (k & 255) << (8 * jj);
            }
            pa[q] = va; pb[q] = vb;
        }
        i32x16 pp = (i32x16)0;
        pp = __builtin_amdgcn_mfma_i32_32x32x32_i8(pa, pb, pp, 0, 0, 0);
#pragma unroll
        for (int r = 0; r < 16; ++r) prow[r] = pp[r] & 31;
    }

    // epilogue: exact i32 partials -> fp64 currents (weights 128^-(c+2))
    const double c128[NS] = {0x1p-14, 0x1p-21, 0x1p-28, 0x1p-35, 0x1p-42};
    const int ocol = o0 + wn + l31;
    const double sbv = (double)sb[ocol];
#pragma unroll
    for (int r = 0; r < 16; ++r) {
        const int trow = bt + wm + prow[r];
        double v = 0.0;
#pragma unroll
        for (int c = 0; c < NS; ++c) v += (double)acc[c][r] * c128[c];
        v *= (double)sa[(size_t)b * tca + trow] * sbv;
        if (t0 + trow < NT)
            cur[((size_t)trow * NB + b) * NO + ocol] = v;
    }
}

// LIF scan: one thread per (b,o); cur chunk is [tc][b*NO+o] fp64. 32-step
// double buffer; 128B contiguous stores per thread per iter. (Unchanged, proven.)
#define NC 32
__global__ __launch_bounds__(64)
void snn_scan_f64(const double* __restrict__ cur, float* __restrict__ out,
                  double* __restrict__ vstate, int t0, int len)
{
    const int gid = blockIdx.x * 64 + threadIdx.x;   // b*NO + o
    const double dt = 0.001 / 50.0;                  // MS / TAU, IEEE double

    double v = (t0 == 0) ? 0.0 : vstate[gid];
    const double* cp = cur + gid;                    // stride NB*NO per t-step
    float* op = out + (size_t)gid * NT + t0;         // thread-contiguous in t

    const size_t ts = (size_t)NB * NO;               // 32768
    const int nb = len / NC;                         // full 32-blocks
    const int rem = len - nb * NC;                   // tail (multiple of 8)

    double A[NC], B[NC];
#pragma unroll
    for (int j = 0; j < NC; ++j) A[j] = (j < len) ? cp[(size_t)j * ts] : 0.0;

    for (int blk = 0; blk < nb; ++blk) {
        const int next = (blk + 1) * NC;
#pragma unroll
        for (int j = 0; j < NC; ++j)
            B[j] = (next + j < len) ? cp[(size_t)(next + j) * ts] : 0.0;

#pragma unroll
        for (int q = 0; q < NC; q += 8) {
            float s[8];
#pragma unroll
            for (int j = 0; j < 8; ++j) {
                v = v + (A[q + j] - v) * dt;
                const bool sp = (v >= 1.0);
                s[j] = sp ? 1.0f : 0.0f;
                if (sp) v = 0.0;
            }
            *(float4*)(op + q)     = make_float4(s[0], s[1], s[2], s[3]);
            *(float4*)(op + q + 4) = make_float4(s[4], s[5], s[6], s[7]);
        }
        op += NC;
#pragma unroll
        for (int j = 0; j < NC; ++j) A[j] = B[j];
    }

    for (int q = 0; q < rem; q += 8) {               // tail (data already in A)
        float s[8];
#pragma unroll
        for (int j = 0; j < 8; ++j) {
            v = v + (A[q + j] - v) * dt;
            const bool sp = (v >= 1.0);
            s[j] = sp ? 1.0f : 0.0f;
            if (sp) v = 0.0;
        }
        *(float4*)(op + q)     = make_float4(s[0], s[1], s[2], s[3]);
        *(float4*)(op + q + 4) = make_float4(s[4], s[5], s[6], s[7]);
    }
    vstate[gid] = v;
}

extern "C" void kernel_launch(void* const* d_in, const int* in_sizes, int n_in,
                              void* d_out, int out_size, void* d_ws, size_t ws_size,
                              hipStream_t stream)
{
    const float* x = (const float*)d_in[0];
    const float* w = (const float*)d_in[1];
    float* out = (float*)d_out;

    char* p = (char*)d_ws;
    double* vstate = (double*)p;         p += (size_t)NB * NO * 8;       // 256KB
    float* sbv = (float*)p;              p += (size_t)2 * NO * 4;        // 8KB
    signed char* wp = (signed char*)p;   p += (size_t)(NO / 64) * NKB * TILEB;  // 5.2MB

    const size_t fixed = (size_t)(p - (char*)d_ws);
    const size_t per_t = (size_t)NB * 4                // SA
                       + (size_t)NS * NB * NI          // x slices (tiled)
                       + (size_t)NB * NO * 8;          // cur
    int tca = 512;                                     // t-chunk, multiple of 64
    while (tca > 64 && fixed + (size_t)tca * per_t > ws_size) tca -= 64;

    float* sa = (float*)p;               p += (size_t)NB * tca * 4;
    signed char* xpl = (signed char*)p;  p += (size_t)NB * (tca / 64) * NKB * TILEB;
    double* cur = (double*)p;

    snn_wscale<<<dim3(NO / 64), dim3(256), 0, stream>>>(w, sbv);
    snn_wslice<<<dim3(NO / 64, NI / 64), dim3(256), 0, stream>>>(w, sbv, wp);

    for (int t0 = 0; t0 < NT; t0 += tca) {
        const int len = (NT - t0 < tca) ? (NT - t0) : tca;
        const int ntiles = (len + BT - 1) / BT;
        snn_xscale<<<dim3(ntiles, NB), dim3(256), 0, stream>>>(x, sa, t0, tca);
        snn_xslice<<<dim3(ntiles, NB, 4), dim3(256), 0, stream>>>(x, sa, xpl, t0, tca, ntiles);
        snn_gemm_i8<<<dim3(NO / BO, ntiles, NB), dim3(256), 0, stream>>>(
            xpl, wp, sa, sbv, cur, t0, tca, ntiles);
        snn_scan_f64<<<dim3((NB * NO) / 64), dim3(64), 0, stream>>>(
            cur, out, vstate, t0, len);
    }
}

// Round 8
// 1040.402 us; speedup vs baseline: 1.0305x; 1.0305x over previous
//
#include <hip/hip_runtime.h>

// SNN layer, round 15: int8 Ozaki GEMM — 32x64 wave tile (A-frag reuse x2).
//
//  Model fitting r9-r14 (all counters): wall/CU/iter = matrix + LDS + L1
//  SERIALIZED + latency overhead. r13: 2196+1875+760=4836 meas; r14:
//  1645+703+937+440=3722 meas. Schedules only move time between pipes;
//  the lever is BYTES PER MFMA.
//
//  This round: wave computes 32t x 64o (two 32x32 o-subtiles):
//   - A frags (5 reads) reused for both subtiles -> 512 B/MFMA (was 682)
//   - block 64t x 128o: DMA 30KB/kb feeds 120 wave-MFMAs (was 20KB/80)
//   - LDS 60KB (2 slots x (A 10KB + B 20KB)), acc[2][5]=160 regs ->
//     2 blocks/CU, launch_bounds(256,2)
//   - schedule/sync IDENTICAL to proven r13: STAGE(kb+1); COMPUTE(kb);
//     vmcnt(0) (hidden under 30 MFMAs); lgkm(0); barrier
//  wp re-tiled to 128-o planes [otile8][kb][s][kc][o128][16] (wslice
//  scatter updated, same swizzle). xp/A layout + all other kernels as r13.
//
//  Numerics unchanged (absmax 0.0 proven: 5 slices base-128, 15 pairs c<=4,
//  i32 exact, fp64 recombine).
//
//  ws: vstate 256KB | SB 8KB | wp 5MB | SA | xp (tiled) | cur (tca=512: 219MB)

#define NB 32
#define NI 1024
#define NO 1024
#define NT 1000
#define NS 5            // slices per operand (7 bits each, base 128)
#define BT 64           // t rows per block tile
#define BO 128          // o cols per block tile
#define KI 32           // k per pipeline stage
#define NKB (NI/KI)     // 32 k-blocks
#define TILEB (NS*2*64*16)     // A: 10240 B per (kb): [s][kc][t64][16]
#define B_TILEB (NS*2*128*16)  // B: 20480 B per (kb): [s][kc][o128][16]

typedef int i32x4  __attribute__((ext_vector_type(4)));
typedef int i32x16 __attribute__((ext_vector_type(16)));

typedef const __attribute__((address_space(1))) void GVOID;
typedef __attribute__((address_space(3))) void LVOID;
#define GLDS16(g, l) __builtin_amdgcn_global_load_lds((GVOID*)(g), (LVOID*)(l), 16, 0, 0)

// ---- per-o column scale of w: SB = 2^(e+1) > colmax, plus 1/SB ----
__global__ void snn_wscale(const float* __restrict__ w, float* __restrict__ sb)
{
    __shared__ float red[4][64];
    const int tid = threadIdx.x;
    const int ol = tid & 63, iq = tid >> 6;
    const int o = blockIdx.x * 64 + ol;
    float m = 0.f;
    for (int i = iq; i < NI; i += 4) m = fmaxf(m, fabsf(w[(size_t)i * NO + o]));
    red[iq][ol] = m;
    __syncthreads();
    if (iq == 0) {
        m = fmaxf(fmaxf(red[0][ol], red[1][ol]), fmaxf(red[2][ol], red[3][ol]));
        const int e = (__float_as_uint(m) >> 23) & 255;
        float S = 0.f, Si = 0.f;
        if (e) {
            S  = __uint_as_float((unsigned)(e + 1) << 23);
            Si = __uint_as_float((unsigned)(253 - e) << 23);
        }
        sb[o] = S;
        sb[NO + o] = Si;
    }
}

// ---- slice w into tiled planes wp[otile8][kb][s][kc][o128][16] (5 slices) ----
__global__ void snn_wslice(const float* __restrict__ w, const float* __restrict__ sb,
                           signed char* __restrict__ wp)
{
    __shared__ int sldw[NS][64][16];   // XOR-swizzled dword cols
    const int tid = threadIdx.x;
    const int ol = tid & 63, iq = tid >> 6;
    const int o0 = blockIdx.x * 64, ic = blockIdx.y * 64;
    const float inv = sb[NO + o0 + ol];
#pragma unroll
    for (int q4 = 0; q4 < 16; q4 += 4) {
        int pk[NS] = {0, 0, 0, 0, 0};
#pragma unroll
        for (int j = 0; j < 4; ++j) {
            const int i = ic + iq * 16 + q4 + j;
            float wv = w[(size_t)i * NO + o0 + ol] * inv;   // exact (pow2 scale)
#pragma unroll
            for (int s = 0; s < NS; ++s) {
                const float f = wv * 128.f;     // exact, |f|<128
                const int a = (int)f;           // trunc in [-127,127]
                wv = f - (float)a;              // exact remainder
                pk[s] |= (a & 255) << (8 * j);
            }
        }
        const int cdw = (iq * 16 + q4) >> 2;
#pragma unroll
        for (int s = 0; s < NS; ++s) sldw[s][ol][cdw ^ (ol & 15)] = pk[s];
    }
    __syncthreads();
    // scatter into 128-o B planes: dword = (s*2+kc)*512 + (o64+r)*4 + d4
    const int o64 = o0 & 64;
    signed char* tb = wp + (size_t)(o0 >> 7) * (NKB * B_TILEB)
                         + (size_t)(ic >> 5) * B_TILEB;
#pragma unroll
    for (int p = 0; p < 20; ++p) {
        const int idx = p * 256 + tid;
        const int kbi = idx >= 2560;
        const int ld  = idx - (kbi ? 2560 : 0);
        const int s  = ld >> 9;
        const int kc = (ld >> 8) & 1;
        const int r  = (ld >> 2) & 63;
        const int d4 = ld & 3;
        const int dofs = (s * 2 + kc) * 512 + (o64 + r) * 4 + d4;
        *(int*)&tb[(size_t)kbi * B_TILEB + (size_t)dofs * 4] =
            sldw[s][r][(kbi * 8 + kc * 4 + d4) ^ (r & 15)];
    }
}

// ---- per-(b,t) scale SA = 2^(e+1) > rowmax ----
__global__ void snn_xscale(const float* __restrict__ x, float* __restrict__ sa,
                           int t0, int tca)
{
    __shared__ float red[4][64];
    const int tid = threadIdx.x;
    const int tl = tid & 63, iq = tid >> 6;
    const int b = blockIdx.y;
    const int tt = blockIdx.x * 64;
    const int tg = t0 + tt + tl;
    const float* xb = x + (size_t)b * NI * NT;
    float m = 0.f;
    if (tg < NT)
        for (int i = iq; i < NI; i += 4) m = fmaxf(m, fabsf(xb[(size_t)i * NT + tg]));
    red[iq][tl] = m;
    __syncthreads();
    if (iq == 0) {
        m = fmaxf(fmaxf(red[0][tl], red[1][tl]), fmaxf(red[2][tl], red[3][tl]));
        const int e = (__float_as_uint(m) >> 23) & 255;
        sa[(size_t)b * tca + tt + tl] = e ? __uint_as_float((unsigned)(e + 1) << 23) : 0.f;
    }
}

// ---- slice x into tiled planes xp[b][tile][kb][s][kc][t][16] (5 slices) ----
__global__ void snn_xslice(const float* __restrict__ x, const float* __restrict__ sa,
                           signed char* __restrict__ xp, int t0, int tca, int ntiles)
{
    __shared__ int sldw[NS][64][16];
    const int tid = threadIdx.x;
    const int tl = tid & 63, iq = tid >> 6;
    const int b = blockIdx.y;
    const int tile = blockIdx.x;
    const int tg = t0 + tile * 64 + tl;
    const bool valid = (tg < NT);
    const float* xb = x + (size_t)b * NI * NT;
    const float S = sa[(size_t)b * tca + tile * 64 + tl];
    const float inv = (S > 0.f)
        ? __uint_as_float((254u - (__float_as_uint(S) >> 23)) << 23) : 0.f;  // exact 1/S
    signed char* tb = xp + (size_t)(b * ntiles + tile) * (NKB * TILEB);

    for (int c4 = 0; c4 < 4; ++c4) {
        const int ic = blockIdx.z * 256 + c4 * 64;
#pragma unroll
        for (int q4 = 0; q4 < 16; q4 += 4) {
            int pk[NS] = {0, 0, 0, 0, 0};
#pragma unroll
            for (int j = 0; j < 4; ++j) {
                const int i = ic + iq * 16 + q4 + j;
                float wv = valid ? xb[(size_t)i * NT + tg] * inv : 0.f;
#pragma unroll
                for (int s = 0; s < NS; ++s) {
                    const float f = wv * 128.f;
                    const int a = (int)f;
                    wv = f - (float)a;
                    pk[s] |= (a & 255) << (8 * j);
                }
            }
            const int cdw = (iq * 16 + q4) >> 2;
#pragma unroll
            for (int s = 0; s < NS; ++s) sldw[s][tl][cdw ^ (tl & 15)] = pk[s];
        }
        __syncthreads();
        signed char* kbb = tb + (size_t)(ic >> 5) * TILEB;
#pragma unroll
        for (int p = 0; p < 20; ++p) {
            const int idx = p * 256 + tid;
            const int kbi = idx >= 2560;
            const int ld  = idx - (kbi ? 2560 : 0);
            const int s  = ld >> 9;
            const int kc = (ld >> 8) & 1;
            const int r  = (ld >> 2) & 63;
            const int d4 = ld & 3;
            *(int*)&kbb[(size_t)kbi * TILEB + (size_t)ld * 4] =
                sldw[s][r][(kbi * 8 + kc * 4 + d4) ^ (r & 15)];
        }
        __syncthreads();
    }
}

// ---- int8 MFMA GEMM: 64t x 128o block, 4 waves of 32t x 64o ----
// 2-slot LDS (60KB), r13-proven 1-barrier loop, A-frags reused across the
// wave's two 32x32 o-subtiles (512 B LDS-read per MFMA, was 682).
__global__ __launch_bounds__(256, 2)
void snn_gemm_i8(const signed char* __restrict__ xp, const signed char* __restrict__ wp,
                 const float* __restrict__ sa, const float* __restrict__ sb,
                 double* __restrict__ cur, int t0, int tca, int ntiles)
{
    __shared__ signed char As[2][TILEB];     // 20 KB
    __shared__ signed char Bs[2][B_TILEB];   // 40 KB

    const int tid  = threadIdx.x;
    const int lane = tid & 63;
    const int wave = tid >> 6;
    const int wm = (wave >> 1) * 32;       // t offset of wave tile
    const int wnb = (wave & 1) * 64;       // o offset of wave tile (64 wide)
    const int l31 = lane & 31;
    const int hi  = lane >> 5;

    // bijective XCD-aware remap (m204); nwg = 256*ntiles, always % 8 == 0
    int lid = blockIdx.x + (int)gridDim.x * (blockIdx.y + (int)gridDim.y * blockIdx.z);
    {
        const int nwg = (int)(gridDim.x * gridDim.y * gridDim.z);
        const int q = nwg >> 3, r = nwg & 7;
        const int xcd = lid & 7, off = lid >> 3;
        lid = (xcd < r ? xcd * (q + 1) : r * (q + 1) + (xcd - r) * q) + off;
    }
    const int ox  = lid & 7;           // o-tile (gridDim.x == 8)
    const int rst = lid >> 3;
    const int ty  = rst % ntiles;      // t-tile
    const int b   = rst / ntiles;      // batch

    const int o0 = ox * BO;
    const int bt = ty * BT;

    i32x16 acc[2][NS];                 // [o-subtile][weight class] = 160 regs
#pragma unroll
    for (int ot = 0; ot < 2; ++ot)
#pragma unroll
        for (int c = 0; c < NS; ++c) acc[ot][c] = (i32x16)0;

    // DMA sources (per-lane) and frag read bases
    const signed char* AgD = xp + (size_t)(b * ntiles + ty) * (NKB * TILEB) + lane * 16;
    const signed char* BgD = wp + (size_t)ox * (NKB * B_TILEB) + lane * 16;
    const int abase  = hi * 1024 + (wm + l31) * 16;            // A: [s][kc][t64][16]
    const int bbase0 = hi * 2048 + (wnb + l31) * 16;           // B: [s][kc][o128][16]
    const int bbase1 = bbase0 + 512;                           // +32 o

    // staging: 30 x 1KB chunks/kb (A 0..9, B 0..19); wave u-slots (wave*8+u)%30
    // -> uniform 8 GLDS16/wave (chunks 0,1 duplicated by wave 3: identical bytes)
#define STAGE(src, bsel) do {                                                  \
    _Pragma("unroll")                                                          \
    for (int u = 0; u < 8; ++u) {                                              \
        int ck = wave * 8 + u; if (ck >= 30) ck -= 30;                         \
        const signed char* g = (ck < 10)                                       \
            ? AgD + (size_t)(src) * TILEB + ck * 1024                          \
            : BgD + (size_t)(src) * B_TILEB + (ck - 10) * 1024;                \
        signed char* l = (ck < 10) ? &As[bsel][0] + ck * 1024                  \
                                   : &Bs[bsel][0] + (ck - 10) * 1024;          \
        GLDS16(g, l);                                                          \
    } } while (0)

    // one k-iteration: 5 A frags (reused x2) + 10 rolling B frags, 30 MFMAs
#define COMPUTE(slot) do {                                                     \
    const signed char* Ab_ = &As[slot][0];                                     \
    const signed char* Bb_ = &Bs[slot][0];                                     \
    i32x4 af[NS];                                                              \
    _Pragma("unroll")                                                          \
    for (int s = 0; s < NS; ++s)                                               \
        af[s] = *(const i32x4*)&Ab_[abase + s * 2048];                         \
    i32x4 bcur = *(const i32x4*)&Bb_[bbase0];                                  \
    _Pragma("unroll")                                                          \
    for (int q = 0; q < 10; ++q) {                                             \
        const int ot = q / 5, j = q % 5;                                       \
        i32x4 bnext = bcur;                                                    \
        if (q + 1 < 10)                                                        \
            bnext = *(const i32x4*)&Bb_[((q + 1) / 5 ? bbase1 : bbase0)        \
                                        + ((q + 1) % 5) * 4096];               \
        __builtin_amdgcn_s_setprio(1);                                         \
        _Pragma("unroll")                                                      \
        for (int i = 0; i + j < NS; ++i)                                       \
            acc[ot][i + j] = __builtin_amdgcn_mfma_i32_32x32x32_i8(            \
                af[i], bcur, acc[ot][i + j], 0, 0, 0);                         \
        __builtin_amdgcn_s_setprio(0);                                         \
        bcur = bnext;                                                          \
    } } while (0)

    // prologue: DMA(0) complete everywhere before first reads
    STAGE(0, 0);
    asm volatile("s_waitcnt vmcnt(0)" ::: "memory");
    __builtin_amdgcn_s_barrier();

    for (int kb = 0; kb < NKB - 1; ++kb) {
        // post-B(kb): all waves' reads of slot[(kb+1)&1] (iter kb-1) drained
        STAGE(kb + 1, (kb + 1) & 1);
        COMPUTE(kb & 1);
        // DMA(kb+1) complete (hidden under the 30 MFMAs) + own reads drained
        asm volatile("s_waitcnt vmcnt(0)" ::: "memory");
        asm volatile("s_waitcnt lgkmcnt(0)" ::: "memory");
        __builtin_amdgcn_sched_barrier(0);
        __builtin_amdgcn_s_barrier();
    }
    COMPUTE((NKB - 1) & 1);   // last k-block: nothing to stage
#undef STAGE
#undef COMPUTE

    // Probe D reg->row mapping (epilogue). A=I(32x32), B[k][n]=k => D[m][n]=m.
    int prow[16];
    {
        i32x4 pa, pb;
#pragma unroll
        for (int q = 0; q < 4; ++q) {
            int va = 0, vb = 0;
#pragma unroll
            for (int jj = 0; jj < 4; ++jj) {
                const int k = 16 * hi + q * 4 + jj;
                if (l31 == k) va |= 1 << (8 * jj);
                vb |= (k & 255) << (8 * jj);
            }
            pa[q] = va; pb[q] = vb;
        }
        i32x16 pp = (i32x16)0;
        pp = __builtin_amdgcn_mfma_i32_32x32x32_i8(pa, pb, pp, 0, 0, 0);
#pragma unroll
        for (int r = 0; r < 16; ++r) prow[r] = pp[r] & 31;
    }

    // epilogue: exact i32 partials -> fp64 currents (weights 128^-(c+2))
    const double c128[NS] = {0x1p-14, 0x1p-21, 0x1p-28, 0x1p-35, 0x1p-42};
#pragma unroll
    for (int ot = 0; ot < 2; ++ot) {
        const int ocol = o0 + wnb + ot * 32 + l31;
        const double sbv = (double)sb[ocol];
#pragma unroll
        for (int r = 0; r < 16; ++r) {
            const int trow = bt + wm + prow[r];
            double v = 0.0;
#pragma unroll
            for (int c = 0; c < NS; ++c) v += (double)acc[ot][c][r] * c128[c];
            v *= (double)sa[(size_t)b * tca + trow] * sbv;
            if (t0 + trow < NT)
                cur[((size_t)trow * NB + b) * NO + ocol] = v;
        }
    }
}

// LIF scan: one thread per (b,o); cur chunk is [tc][b*NO+o] fp64. 32-step
// double buffer; 128B contiguous stores per thread per iter. (Unchanged, proven.)
#define NC 32
__global__ __launch_bounds__(64)
void snn_scan_f64(const double* __restrict__ cur, float* __restrict__ out,
                  double* __restrict__ vstate, int t0, int len)
{
    const int gid = blockIdx.x * 64 + threadIdx.x;   // b*NO + o
    const double dt = 0.001 / 50.0;                  // MS / TAU, IEEE double

    double v = (t0 == 0) ? 0.0 : vstate[gid];
    const double* cp = cur + gid;                    // stride NB*NO per t-step
    float* op = out + (size_t)gid * NT + t0;         // thread-contiguous in t

    const size_t ts = (size_t)NB * NO;               // 32768
    const int nb = len / NC;                         // full 32-blocks
    const int rem = len - nb * NC;                   // tail (multiple of 8)

    double A[NC], B[NC];
#pragma unroll
    for (int j = 0; j < NC; ++j) A[j] = (j < len) ? cp[(size_t)j * ts] : 0.0;

    for (int blk = 0; blk < nb; ++blk) {
        const int next = (blk + 1) * NC;
#pragma unroll
        for (int j = 0; j < NC; ++j)
            B[j] = (next + j < len) ? cp[(size_t)(next + j) * ts] : 0.0;

#pragma unroll
        for (int q = 0; q < NC; q += 8) {
            float s[8];
#pragma unroll
            for (int j = 0; j < 8; ++j) {
                v = v + (A[q + j] - v) * dt;
                const bool sp = (v >= 1.0);
                s[j] = sp ? 1.0f : 0.0f;
                if (sp) v = 0.0;
            }
            *(float4*)(op + q)     = make_float4(s[0], s[1], s[2], s[3]);
            *(float4*)(op + q + 4) = make_float4(s[4], s[5], s[6], s[7]);
        }
        op += NC;
#pragma unroll
        for (int j = 0; j < NC; ++j) A[j] = B[j];
    }

    for (int q = 0; q < rem; q += 8) {               // tail (data already in A)
        float s[8];
#pragma unroll
        for (int j = 0; j < 8; ++j) {
            v = v + (A[q + j] - v) * dt;
            const bool sp = (v >= 1.0);
            s[j] = sp ? 1.0f : 0.0f;
            if (sp) v = 0.0;
        }
        *(float4*)(op + q)     = make_float4(s[0], s[1], s[2], s[3]);
        *(float4*)(op + q + 4) = make_float4(s[4], s[5], s[6], s[7]);
    }
    vstate[gid] = v;
}

extern "C" void kernel_launch(void* const* d_in, const int* in_sizes, int n_in,
                              void* d_out, int out_size, void* d_ws, size_t ws_size,
                              hipStream_t stream)
{
    const float* x = (const float*)d_in[0];
    const float* w = (const float*)d_in[1];
    float* out = (float*)d_out;

    char* p = (char*)d_ws;
    double* vstate = (double*)p;         p += (size_t)NB * NO * 8;       // 256KB
    float* sbv = (float*)p;              p += (size_t)2 * NO * 4;        // 8KB
    signed char* wp = (signed char*)p;   p += (size_t)(NO / BO) * NKB * B_TILEB; // 5MB

    const size_t fixed = (size_t)(p - (char*)d_ws);
    const size_t per_t = (size_t)NB * 4                // SA
                       + (size_t)NS * NB * NI          // x slices (tiled)
                       + (size_t)NB * NO * 8;          // cur
    int tca = 512;                                     // t-chunk, multiple of 64
    while (tca > 64 && fixed + (size_t)tca * per_t > ws_size) tca -= 64;

    float* sa = (float*)p;               p += (size_t)NB * tca * 4;
    signed char* xpl = (signed char*)p;  p += (size_t)NB * (tca / 64) * NKB * TILEB;
    double* cur = (double*)p;

    snn_wscale<<<dim3(NO / 64), dim3(256), 0, stream>>>(w, sbv);
    snn_wslice<<<dim3(NO / 64, NI / 64), dim3(256), 0, stream>>>(w, sbv, wp);

    for (int t0 = 0; t0 < NT; t0 += tca) {
        const int len = (NT - t0 < tca) ? (NT - t0) : tca;
        const int ntiles = (len + BT - 1) / BT;
        snn_xscale<<<dim3(ntiles, NB), dim3(256), 0, stream>>>(x, sa, t0, tca);
        snn_xslice<<<dim3(ntiles, NB, 4), dim3(256), 0, stream>>>(x, sa, xpl, t0, tca, ntiles);
        snn_gemm_i8<<<dim3(NO / BO, ntiles, NB), dim3(256), 0, stream>>>(
            xpl, wp, sa, sbv, cur, t0, tca, ntiles);
        snn_scan_f64<<<dim3((NB * NO) / 64), dim3(64), 0, stream>>>(
            cur, out, vstate, t0, len);
    }
}